// Round 14
// baseline (373.987 us; speedup 1.0000x reference)
//
#include <hip/hip_runtime.h>
#include <stdint.h>

// EETQLinear w8a16: out[m,n] = (sum_k x[m,k]*wq[k,n]) * scale[n] + bias[n]
// M=8192, K=4096, N=4096. Dtypes (r3/r4-verified): x/scale/bias/out f32, wq int32.
// v14: 1-WAVE/SIMD BIG-TILE. 4 waves/block, wave tile 128x128 (acc 256 VGPR),
//      block tile 256x256, BK=64. Operands PRE-PERMUTED in d_ws to a
//      [rowblock][ktile][ks][rowgroup][k-major 1KB subtile] layout:
//        - staging = 16 global_load_lds from contiguous 32KB (perfect coalesce)
//        - fragment ds_reads are lane-linear (base + l*16): conflict-free, no swizzle
//      Window: VMC0+BARR; STAGE(next->other buf); 32 ds_reads; lgkm(15); 64 MFMA;
//      lgkm(0); 64 MFMA. One barrier/window, counted waits (rule-18 sched_barrier).

typedef __attribute__((ext_vector_type(4))) float     f32x4;
typedef __attribute__((ext_vector_type(8))) _Float16  f16x8;

#define M_DIM 8192
#define N_DIM 4096
#define K_DIM 4096

// ---------------- prologue: x f32 -> XhPerm (permuted f16) ----------------
// XhPerm byte layout: [rb(32)][kt(64)] 32KB regions; region = ks*16384 + rg*1024
// + kc*256 + row*16  (rg=rowgroup of 16 rows, kc=k-chunk of 8, row in group).
__global__ __launch_bounds__(256) void convert_x_perm(const float* __restrict__ x,
                                                      char* __restrict__ XhP) {
    __shared__ _Float16 tile[64 * 72];            // [row][k], stride 72 (16B-aligned rows)
    const int rb64 = blockIdx.x;                  // 0..127 (64-row slabs)
    const int kt   = blockIdx.y;                  // 0..63
    const int t    = threadIdx.x;
    const int r    = t >> 2;                      // 0..63
    const int c4   = (t & 3) * 16;                // k offset 0/16/32/48
    const float* src = x + (size_t)(rb64 * 64 + r) * K_DIM + kt * 64 + c4;
    f16x8 h0, h1;
#pragma unroll
    for (int j = 0; j < 4; ++j) {
        float4 v = ((const float4*)src)[j];
        _Float16 e0 = (_Float16)v.x, e1 = (_Float16)v.y;
        _Float16 e2 = (_Float16)v.z, e3 = (_Float16)v.w;
        if (j < 2) { h0[j*4+0]=e0; h0[j*4+1]=e1; h0[j*4+2]=e2; h0[j*4+3]=e3; }
        else       { h1[(j-2)*4+0]=e0; h1[(j-2)*4+1]=e1; h1[(j-2)*4+2]=e2; h1[(j-2)*4+3]=e3; }
    }
    *(f16x8*)&tile[r * 72 + c4]     = h0;
    *(f16x8*)&tile[r * 72 + c4 + 8] = h1;
    __syncthreads();
    char* outB = XhP + ((size_t)(rb64 >> 2) * 64 + kt) * 32768
                     + (size_t)((rb64 & 3) * 4) * 1024;
#pragma unroll
    for (int i = 0; i < 2; ++i) {
        const int c   = t + i * 256;              // 0..511
        const int row = c & 15, kc = (c >> 4) & 3, rgl = (c >> 6) & 3, ks = (c >> 8) & 1;
        f16x8 v = *(const f16x8*)&tile[(rgl * 16 + row) * 72 + ks * 32 + kc * 8];
        *(f16x8*)(outB + ks * 16384 + rgl * 1024 + kc * 256 + row * 16) = v;
    }
}

// ---------------- prologue: wq int32 [K][N] -> WtPerm (transposed+permuted f16) ----
__global__ __launch_bounds__(256) void dequant_w_perm(const int* __restrict__ wq,
                                                      char* __restrict__ WtP) {
    __shared__ _Float16 tileT[64 * 72];           // [n][k], stride 72
    const int nb64 = blockIdx.x;                  // 0..63 (64-col slabs)
    const int kt   = blockIdx.y;                  // 0..63
    const int t    = threadIdx.x;
    const int r    = t >> 2;                      // k-row 0..63
    const int c4   = (t & 3) * 16;                // n offset
    const int* src = wq + (size_t)(kt * 64 + r) * N_DIM + nb64 * 64 + c4;
#pragma unroll
    for (int j = 0; j < 4; ++j) {
        int4 q = ((const int4*)src)[j];
        tileT[(c4 + j * 4 + 0) * 72 + r] = (_Float16)q.x;
        tileT[(c4 + j * 4 + 1) * 72 + r] = (_Float16)q.y;
        tileT[(c4 + j * 4 + 2) * 72 + r] = (_Float16)q.z;
        tileT[(c4 + j * 4 + 3) * 72 + r] = (_Float16)q.w;
    }
    __syncthreads();
    char* outB = WtP + ((size_t)(nb64 >> 2) * 64 + kt) * 32768
                     + (size_t)((nb64 & 3) * 4) * 1024;
#pragma unroll
    for (int i = 0; i < 2; ++i) {
        const int c    = t + i * 256;
        const int ncol = c & 15, kc = (c >> 4) & 3, ngl = (c >> 6) & 3, ks = (c >> 8) & 1;
        f16x8 v = *(const f16x8*)&tileT[(ngl * 16 + ncol) * 72 + ks * 32 + kc * 8];
        *(f16x8*)(outB + ks * 16384 + ngl * 1024 + kc * 256 + ncol * 16) = v;
    }
}

// ---------------- 1-wave/SIMD big-tile GEMM ----------------
#define AS1C(p) (const __attribute__((address_space(1))) void*)(p)
#define AS3C(p) (__attribute__((address_space(3))) void*)(p)

// stage K-tile tl (32KB A + 32KB B, both contiguous) into buffer at BOFF
#define STAGE(BOFF, tl) do {                                                          \
    const char* sa_ = srcA + (size_t)(tl) * 32768;                                    \
    const char* sb_ = srcB + (size_t)(tl) * 32768;                                    \
    _Pragma("unroll")                                                                 \
    for (int i_ = 0; i_ < 8; ++i_) {                                                  \
        __builtin_amdgcn_global_load_lds(AS1C(sa_ + i_ * 4096),                       \
            AS3C(ldsBase + (BOFF) + i_ * 4096 + t * 16), 16, 0, 0);                   \
        __builtin_amdgcn_global_load_lds(AS1C(sb_ + i_ * 4096),                       \
            AS3C(ldsBase + (BOFF) + 32768 + i_ * 4096 + t * 16), 16, 0, 0);           \
    }                                                                                 \
} while (0)

#define DSR(dst, addr, IMM) \
    asm volatile("ds_read_b128 %0, %1 offset:%c2" : "=v"(dst) : "v"(addr), "i"(IMM))

// set0 (k-step 0) -> a0_..a7_, b0_..b7_ ; set1 (k-step 1, +16384) -> c.., d..
#define READS0(AR, BR)                                           \
    DSR(a0_, AR, 0);     DSR(a1_, AR, 1024);  DSR(a2_, AR, 2048);  DSR(a3_, AR, 3072); \
    DSR(a4_, AR, 4096);  DSR(a5_, AR, 5120);  DSR(a6_, AR, 6144);  DSR(a7_, AR, 7168); \
    DSR(b0_, BR, 0);     DSR(b1_, BR, 1024);  DSR(b2_, BR, 2048);  DSR(b3_, BR, 3072); \
    DSR(b4_, BR, 4096);  DSR(b5_, BR, 5120);  DSR(b6_, BR, 6144);  DSR(b7_, BR, 7168)
#define READS1(AR, BR)                                           \
    DSR(c0_, AR, 16384); DSR(c1_, AR, 17408); DSR(c2_, AR, 18432); DSR(c3_, AR, 19456); \
    DSR(c4_, AR, 20480); DSR(c5_, AR, 21504); DSR(c6_, AR, 22528); DSR(c7_, AR, 23552); \
    DSR(d0_, BR, 16384); DSR(d1_, BR, 17408); DSR(d2_, BR, 18432); DSR(d3_, BR, 19456); \
    DSR(d4_, BR, 20480); DSR(d5_, BR, 21504); DSR(d6_, BR, 22528); DSR(d7_, BR, 23552)

#define MM(AI, BI, AV, BV) \
    acc[AI][BI] = __builtin_amdgcn_mfma_f32_16x16x32_f16(AV, BV, acc[AI][BI], 0, 0, 0)

#define ROW8(AI, AV, B0, B1, B2, B3, B4, B5, B6, B7)                                  \
    MM(AI, 0, AV, B0); MM(AI, 1, AV, B1); MM(AI, 2, AV, B2); MM(AI, 3, AV, B3);       \
    MM(AI, 4, AV, B4); MM(AI, 5, AV, B5); MM(AI, 6, AV, B6); MM(AI, 7, AV, B7)

#define MFMA64_0()                                                                    \
    ROW8(0, a0_, b0_, b1_, b2_, b3_, b4_, b5_, b6_, b7_);                             \
    ROW8(1, a1_, b0_, b1_, b2_, b3_, b4_, b5_, b6_, b7_);                             \
    ROW8(2, a2_, b0_, b1_, b2_, b3_, b4_, b5_, b6_, b7_);                             \
    ROW8(3, a3_, b0_, b1_, b2_, b3_, b4_, b5_, b6_, b7_);                             \
    ROW8(4, a4_, b0_, b1_, b2_, b3_, b4_, b5_, b6_, b7_);                             \
    ROW8(5, a5_, b0_, b1_, b2_, b3_, b4_, b5_, b6_, b7_);                             \
    ROW8(6, a6_, b0_, b1_, b2_, b3_, b4_, b5_, b6_, b7_);                             \
    ROW8(7, a7_, b0_, b1_, b2_, b3_, b4_, b5_, b6_, b7_)
#define MFMA64_1()                                                                    \
    ROW8(0, c0_, d0_, d1_, d2_, d3_, d4_, d5_, d6_, d7_);                             \
    ROW8(1, c1_, d0_, d1_, d2_, d3_, d4_, d5_, d6_, d7_);                             \
    ROW8(2, c2_, d0_, d1_, d2_, d3_, d4_, d5_, d6_, d7_);                             \
    ROW8(3, c3_, d0_, d1_, d2_, d3_, d4_, d5_, d6_, d7_);                             \
    ROW8(4, c4_, d0_, d1_, d2_, d3_, d4_, d5_, d6_, d7_);                             \
    ROW8(5, c5_, d0_, d1_, d2_, d3_, d4_, d5_, d6_, d7_);                             \
    ROW8(6, c6_, d0_, d1_, d2_, d3_, d4_, d5_, d6_, d7_);                             \
    ROW8(7, c7_, d0_, d1_, d2_, d3_, d4_, d5_, d6_, d7_)

#define BARR()   __builtin_amdgcn_s_barrier()
#define SB0()    __builtin_amdgcn_sched_barrier(0)
#define LGKM0()  do { asm volatile("s_waitcnt lgkmcnt(0)"  ::: "memory"); SB0(); } while (0)
#define LGKM15() do { asm volatile("s_waitcnt lgkmcnt(15)" ::: "memory"); SB0(); } while (0)
#define VMC0()   asm volatile("s_waitcnt vmcnt(0)" ::: "memory")
#define PRIO1()  __builtin_amdgcn_s_setprio(1)
#define PRIO0()  __builtin_amdgcn_s_setprio(0)

// Window j: tile j's 16 DMAs (issued last window) drained by VMC0; BARR also
// broadcasts "other buffer's reads done" (each wave's LGKM0 preceded arrival).
// Then stage tile j+1 into the freed buffer, read+compute tile j.
#define WINDOW(AR, BR, SOFF, tl) do {                                                 \
    VMC0(); BARR();                                                                   \
    STAGE(SOFF, tl);                                                                  \
    READS0(AR, BR);                                                                   \
    READS1(AR, BR);                                                                   \
    LGKM15();                               /* 32 issued; <=15 left => set0 done */   \
    PRIO1(); MFMA64_0(); PRIO0();                                                     \
    LGKM0();                                /* set1 done (drained under MFMA0) */     \
    PRIO1(); MFMA64_1(); PRIO0();                                                     \
} while (0)

__global__ __launch_bounds__(256, 1) void gemm_big(const char* __restrict__ XhP,
                                                   const char* __restrict__ WtP,
                                                   const float* __restrict__ scale,
                                                   const float* __restrict__ bias,
                                                   float* __restrict__ C) {
    __shared__ __attribute__((aligned(128))) _Float16 L[65536];   // 2 x 64KB buffers
    char* ldsBase = (char*)L;

    // T1: XCD-aware bijective swizzle (512 blocks, 512 % 8 == 0)
    const int bid = blockIdx.x;
    const int swz = (bid & 7) * 64 + (bid >> 3);
    const int bm  = swz >> 4;            // 0..31
    const int bn  = swz & 15;            // 0..15

    const int t  = threadIdx.x;          // 0..255
    const int l  = t & 63;
    const int w  = t >> 6;               // 4 waves: 2(M) x 2(N), 128x128 out each
    const int wm = w >> 1, wn = w & 1;
    const int lr = l & 15, lh = l >> 4;

    const char* srcA = XhP + (size_t)(bm * 64) * 32768 + (size_t)t * 16;
    const char* srcB = WtP + (size_t)(bn * 64) * 32768 + (size_t)t * 16;

    // lane-linear fragment addresses: subtile = 1KB, lane reads base + l*16
    const uint32_t aX = (uint32_t)(uintptr_t)L + (uint32_t)(wm * 8192 + l * 16);
    const uint32_t bX = (uint32_t)(uintptr_t)L + 32768u + (uint32_t)(wn * 8192 + l * 16);
    const uint32_t aY = aX + 65536u;
    const uint32_t bY = bX + 65536u;

    f16x8 a0_, a1_, a2_, a3_, a4_, a5_, a6_, a7_;
    f16x8 b0_, b1_, b2_, b3_, b4_, b5_, b6_, b7_;
    f16x8 c0_, c1_, c2_, c3_, c4_, c5_, c6_, c7_;
    f16x8 d0_, d1_, d2_, d3_, d4_, d5_, d6_, d7_;
    f32x4 acc[8][8] = {};

    STAGE(0, 0);                          // tile 0 -> X (16 DMA outstanding)

#pragma unroll 1
    for (int it = 0; it < 32; ++it) {     // 64 K-tiles, 2 windows each
        WINDOW(aX, bX, 65536, 2 * it + 1);          // read X(tile 2it), stage->Y
        WINDOW(aY, bY, 0, (2 * it + 2) & 63);       // read Y(tile 2it+1), stage->X
    }
    VMC0();                               // drain dead final stage

    // epilogue: C/D layout col = lane&15, row = (lane>>4)*4 + reg  [m89-verified]
    const int col0 = bn * 256 + wn * 128 + lr;
    const int row0 = bm * 256 + wm * 128 + lh * 4;
    float sc[8], bi_[8];
#pragma unroll
    for (int ni = 0; ni < 8; ++ni) {
        sc[ni]  = scale[col0 + ni * 16];
        bi_[ni] = bias[col0 + ni * 16];
    }
#pragma unroll
    for (int ai = 0; ai < 8; ++ai)
#pragma unroll
        for (int r = 0; r < 4; ++r) {
            const size_t rowOff = (size_t)(row0 + ai * 16 + r) * N_DIM;
#pragma unroll
            for (int ni = 0; ni < 8; ++ni)
                C[rowOff + col0 + ni * 16] = acc[ai][ni][r] * sc[ni] + bi_[ni];
        }
}

extern "C" void kernel_launch(void* const* d_in, const int* in_sizes, int n_in,
                              void* d_out, int out_size, void* d_ws, size_t ws_size,
                              hipStream_t stream) {
    const float* x     = (const float*)d_in[0];
    const int*   wq    = (const int*)d_in[1];
    const float* scale = (const float*)d_in[2];
    const float* bias  = (const float*)d_in[3];
    float* out = (float*)d_out;

    char* XhP = (char*)d_ws;                                   // 64 MB permuted x
    char* WtP = (char*)d_ws + (size_t)M_DIM * K_DIM * 2;       // 32 MB permuted w
                                                               // total 96MB <= ws (r4)
    convert_x_perm<<<dim3(128, 64), 256, 0, stream>>>(x, XhP);
    dequant_w_perm<<<dim3(64, 64), 256, 0, stream>>>(wq, WtP);

    const int nblocks = (M_DIM / 256) * (N_DIM / 256);         // 512
    gemm_big<<<nblocks, 256, 0, stream>>>(XhP, WtP, scale, bias, out);
}